// Round 1
// baseline (514.605 us; speedup 1.0000x reference)
//
#include <hip/hip_runtime.h>

#define N_NODES 8192
#define CAP 128   // neighbor-list capacity; Binomial(8192,1/256) mean 32, P(>128)~0

// ---------------------------------------------------------------------------
// Pass 1: one scan of adj (256 MB) -> per-row nonzero count, neighbor list,
// dinv = rsqrt(deg+1). This is the HBM-bound kernel; everything else is small.
// ---------------------------------------------------------------------------
__global__ void deg_csr_kernel(const float* __restrict__ adj,
                               int* __restrict__ cnt, int* __restrict__ nbr,
                               float* __restrict__ dinv) {
  __shared__ int s_cnt;
  const int row = blockIdx.x;
  const int t = threadIdx.x;
  if (t == 0) s_cnt = 0;
  __syncthreads();
  const float4* rowp = (const float4*)(adj + (size_t)row * N_NODES);
#pragma unroll
  for (int i = 0; i < 8; ++i) {
    int idx4 = t + i * 256;                 // 2048 float4 per row / 256 threads
    float4 v = rowp[idx4];
    int col = idx4 * 4;
    if (v.x != 0.f) { int p = atomicAdd(&s_cnt, 1); if (p < CAP) nbr[row * CAP + p] = col; }
    if (v.y != 0.f) { int p = atomicAdd(&s_cnt, 1); if (p < CAP) nbr[row * CAP + p] = col + 1; }
    if (v.z != 0.f) { int p = atomicAdd(&s_cnt, 1); if (p < CAP) nbr[row * CAP + p] = col + 2; }
    if (v.w != 0.f) { int p = atomicAdd(&s_cnt, 1); if (p < CAP) nbr[row * CAP + p] = col + 3; }
  }
  __syncthreads();
  if (t == 0) {
    cnt[row] = s_cnt;
    dinv[row] = rsqrtf((float)s_cnt + 1.0f);
  }
}

// ---------------------------------------------------------------------------
// Aggregation: g1 = relu(dinv_i * (msg_i + sum_{j in nbr(i)} msg_j) + bg)
// msg is already pre-scaled by dinv_j. 128 threads = one feature each.
// ---------------------------------------------------------------------------
__global__ void agg_kernel(const int* __restrict__ cnt, const int* __restrict__ nbr,
                           const float* __restrict__ msg, const float* __restrict__ dinv,
                           const float* __restrict__ bg, const float* __restrict__ adj,
                           float* __restrict__ g1) {
  const int row = blockIdx.x;
  const int t = threadIdx.x;  // 0..127
  float acc = msg[(size_t)row * 128 + t];  // self-loop term (a_hat diag = 1)
  const int c = cnt[row];
  if (c <= CAP) {
    for (int i = 0; i < c; ++i) {
      int j = nbr[row * CAP + i];
      acc += msg[(size_t)j * 128 + t];
    }
  } else {
    // correct-but-slow fallback; statistically unreachable for this input
    for (int col = 0; col < N_NODES; ++col) {
      if (adj[(size_t)row * N_NODES + col] != 0.f) acc += msg[(size_t)col * 128 + t];
    }
  }
  float v = fmaf(dinv[row], acc, bg[t]);
  g1[(size_t)row * 128 + t] = fmaxf(v, 0.f);
}

// ---------------------------------------------------------------------------
// Small fp32 GEMM: C[n][f] = A[n][:] . W[f][:] (+bias) (relu) (*rowscale)
// ROWS=32 nodes/block, K in chunks of 32. W staged k-major (padded, conflict-
// free); A staged padded for aligned float4 reads. MODE: 1=bias 2=relu
// 4=rowscale(dinv or mask). CONCAT: logical A = [A | A2], each stride K/2.
// ---------------------------------------------------------------------------
template <int K, int FOUT, int MODE, bool CONCAT>
__launch_bounds__(256)
__global__ void gemm_kernel(const float* __restrict__ A, const float* __restrict__ A2,
                            const float* __restrict__ W, const float* __restrict__ bias,
                            const float* __restrict__ rowscale, float* __restrict__ C) {
  constexpr int ROWS = 32, KC = 32;
  constexpr int NCH = K / KC;
  constexpr int RSTRIDE = 256 / FOUT;   // rows covered per sweep
  constexpr int RPT = ROWS / RSTRIDE;   // accumulators per thread
  __shared__ float A_lds[ROWS][KC + 4];   // row stride 36 floats -> 16B aligned
  __shared__ float W_lds[KC][FOUT + 1];   // k-major, +1 pad -> conflict-free
  const int t = threadIdx.x;
  const int n0 = blockIdx.x * ROWS;
  const int c = t % FOUT;
  const int rbase = t / FOUT;
  float acc[RPT];
#pragma unroll
  for (int i = 0; i < RPT; ++i) acc[i] = 0.f;

  for (int ch = 0; ch < NCH; ++ch) {
    {  // A tile: 32x32 = 256 float4, one per thread, coalesced
      int row = t >> 3, k4 = (t & 7) * 4;
      int kk = ch * KC + k4;
      const float* src;
      if (CONCAT) {
        src = (kk < K / 2) ? (A + (size_t)(n0 + row) * (K / 2) + kk)
                           : (A2 + (size_t)(n0 + row) * (K / 2) + (kk - K / 2));
      } else {
        src = A + (size_t)(n0 + row) * K + kk;
      }
      float4 v = *(const float4*)src;
      *(float4*)&A_lds[row][k4] = v;
    }
#pragma unroll
    for (int i = 0; i < (FOUT * KC) / 256; ++i) {  // W tile, transposed to k-major
      int lin = t + i * 256;
      int k = lin & (KC - 1), f = lin >> 5;
      W_lds[k][f] = W[(size_t)f * K + ch * KC + k];
    }
    __syncthreads();
#pragma unroll
    for (int kg = 0; kg < KC / 4; ++kg) {
      float w0 = W_lds[kg * 4 + 0][c];
      float w1v = W_lds[kg * 4 + 1][c];
      float w2v = W_lds[kg * 4 + 2][c];
      float w3v = W_lds[kg * 4 + 3][c];
#pragma unroll
      for (int i = 0; i < RPT; ++i) {
        const float4 av = *(const float4*)&A_lds[rbase + i * RSTRIDE][kg * 4];
        acc[i] = fmaf(av.x, w0, acc[i]);
        acc[i] = fmaf(av.y, w1v, acc[i]);
        acc[i] = fmaf(av.z, w2v, acc[i]);
        acc[i] = fmaf(av.w, w3v, acc[i]);
      }
    }
    __syncthreads();
  }
#pragma unroll
  for (int i = 0; i < RPT; ++i) {
    int node = n0 + rbase + i * RSTRIDE;
    float v = acc[i];
    if (MODE & 1) v += bias[c];
    if (MODE & 2) v = fmaxf(v, 0.f);
    if (MODE & 4) v *= rowscale[node];
    C[(size_t)node * FOUT + c] = v;
  }
}

extern "C" void kernel_launch(void* const* d_in, const int* in_sizes, int n_in,
                              void* d_out, int out_size, void* d_ws, size_t ws_size,
                              hipStream_t stream) {
  const float* x    = (const float*)d_in[0];
  const float* adj  = (const float*)d_in[1];
  const float* mask = (const float*)d_in[2];
  const float* w1   = (const float*)d_in[3];
  const float* b1   = (const float*)d_in[4];
  const float* w2   = (const float*)d_in[5];
  const float* b2   = (const float*)d_in[6];
  const float* wg   = (const float*)d_in[7];
  const float* bg   = (const float*)d_in[8];
  const float* wd   = (const float*)d_in[9];
  const float* bd   = (const float*)d_in[10];
  const float* wp1  = (const float*)d_in[11];
  const float* bp1  = (const float*)d_in[12];
  const float* wp2  = (const float*)d_in[13];
  const float* bp2  = (const float*)d_in[14];
  const float* wo   = (const float*)d_in[15];
  const float* bo   = (const float*)d_in[16];
  float* out = (float*)d_out;

  float* ws = (float*)d_ws;
  float* h1   = ws; ws += (size_t)N_NODES * 64;
  float* h    = ws; ws += (size_t)N_NODES * 128;
  float* msg  = ws; ws += (size_t)N_NODES * 128;
  float* g1   = ws; ws += (size_t)N_NODES * 128;
  float* g2   = ws; ws += (size_t)N_NODES * 128;
  float* p1   = ws; ws += (size_t)N_NODES * 128;
  float* p2   = ws; ws += (size_t)N_NODES * 64;
  float* dinv = ws; ws += N_NODES;
  int* cnt = (int*)ws; ws += N_NODES;
  int* nbr = (int*)ws;  // N_NODES * CAP ints

  // degree + CSR (independent of encoder; launch first)
  deg_csr_kernel<<<N_NODES, 256, 0, stream>>>(adj, cnt, nbr, dinv);
  // encoder
  gemm_kernel<32, 64, 3, false><<<256, 256, 0, stream>>>(x, nullptr, w1, b1, nullptr, h1);
  gemm_kernel<64, 128, 3, false><<<256, 256, 0, stream>>>(h1, nullptr, w2, b2, nullptr, h);
  // msg = (h @ wg.T) * dinv[row]   (no bias, no relu)
  gemm_kernel<128, 128, 4, false><<<256, 256, 0, stream>>>(h, nullptr, wg, nullptr, dinv, msg);
  // sparse aggregation + bg + relu
  agg_kernel<<<N_NODES, 128, 0, stream>>>(cnt, nbr, msg, dinv, bg, adj, g1);
  // decoder
  gemm_kernel<128, 128, 3, false><<<256, 256, 0, stream>>>(g1, nullptr, wd, bd, nullptr, g2);
  gemm_kernel<256, 128, 3, true><<<256, 256, 0, stream>>>(g2, h, wp1, bp1, nullptr, p1);  // f=[g2|h]
  gemm_kernel<128, 64, 3, false><<<256, 256, 0, stream>>>(p1, nullptr, wp2, bp2, nullptr, p2);
  // out = (p2 @ wo.T + bo) * mask
  gemm_kernel<64, 8, 5, false><<<256, 256, 0, stream>>>(p2, nullptr, wo, bo, mask, out);
}